// Round 3
// baseline (125.185 us; speedup 1.0000x reference)
//
#include <hip/hip_runtime.h>
#include <hip/hip_cooperative_groups.h>

namespace coop = cooperative_groups;

// BeamCTCDecoder — degenerate beam search == per-step argmax, then CTC collapse.
// logits: (N=128, C=128, T=2048) float32, layout n*C*T + c*T + t.
// out: (N, T) int32 — collapsed tokens, blank(0)-padded.
// Single cooperative kernel: phase 1 = argmax (4-way class split, 16 waves/CU),
// grid.sync(), phase 2 = per-row CTC collapse on blocks 0..N-1.

constexpr int N = 128;
constexpr int C = 128;
constexpr int T = 2048;

__global__ __launch_bounds__(256) void fused_kernel(const float* __restrict__ logits,
                                                    int* __restrict__ tokens,
                                                    int* __restrict__ out) {
    // ---------------- Phase 1: argmax over classes, 4-way c-split ----------------
    // Block = 256 threads = 4 waves; wave g scans classes [g*32, g*32+32) for the
    // same 64 t-quads (256 consecutive t's = 1 KiB contiguous per wave load).
    // 8 blocks per row -> 1024 blocks total -> 4 blocks/CU, 16 waves/CU.
    __shared__ float sb[3][64][4];
    __shared__ int   si[3][64][4];

    const int tid = threadIdx.x;
    const int tq  = tid & 63;            // t-quad slot (== lane)
    const int grp = tid >> 6;            // c-group 0..3 (== wave id)
    const int b   = blockIdx.x;
    const int n   = b >> 3;              // 8 blocks per row
    const int t4  = (b & 7) * 256 + tq * 4;

    const float* base = logits + (size_t)n * C * T + (size_t)(grp * 32) * T + t4;

    float4 best = *(const float4*)(base);               // local c = 0
    int4 bidx = make_int4(0, 0, 0, 0);
    #pragma unroll 8
    for (int c = 1; c < 32; ++c) {
        float4 v = *(const float4*)(base + (size_t)c * T);
        // strict > keeps the FIRST max (matches jnp.argmax tie-break)
        if (v.x > best.x) { best.x = v.x; bidx.x = c; }
        if (v.y > best.y) { best.y = v.y; bidx.y = c; }
        if (v.z > best.z) { best.z = v.z; bidx.z = c; }
        if (v.w > best.w) { best.w = v.w; bidx.w = c; }
    }

    if (grp > 0) {                                      // waves 1-3 publish
        *(float4*)sb[grp - 1][tq] = best;
        int4 gi = make_int4(bidx.x + grp * 32, bidx.y + grp * 32,
                            bidx.z + grp * 32, bidx.w + grp * 32);
        *(int4*)si[grp - 1][tq] = gi;
    }
    __syncthreads();
    if (grp == 0) {                                     // wave 0 combines + writes
        #pragma unroll
        for (int g = 0; g < 3; ++g) {
            float4 ob = *(float4*)sb[g][tq];
            int4   oi = *(int4*)si[g][tq];
            // higher groups win only on strict > -> ties keep lowest class
            if (ob.x > best.x) { best.x = ob.x; bidx.x = oi.x; }
            if (ob.y > best.y) { best.y = ob.y; bidx.y = oi.y; }
            if (ob.z > best.z) { best.z = ob.z; bidx.z = oi.z; }
            if (ob.w > best.w) { best.w = ob.w; bidx.w = oi.w; }
        }
        *(int4*)(tokens + (size_t)n * T + t4) = bidx;
    }

    coop::this_grid().sync();

    // ---------------- Phase 2: per-row CTC collapse (blocks 0..N-1) ----------------
    if (b >= N) return;
    const int* trow = tokens + (size_t)b * T;
    int* orow = out + (size_t)b * T;
    constexpr int PER = T / 256;            // 8
    const int t0 = tid * PER;

    int tok[PER];
    *(int4*)&tok[0] = *(const int4*)(trow + t0);
    *(int4*)&tok[4] = *(const int4*)(trow + t0 + 4);
    int prev = (t0 == 0) ? -1 : trow[t0 - 1];

    int kpos[PER];
    int cnt = 0;
    #pragma unroll
    for (int i = 0; i < PER; ++i) {
        const bool k = (tok[i] != 0) && (tok[i] != prev);
        kpos[i] = k ? cnt : -1;
        cnt += k ? 1 : 0;
        prev = tok[i];
    }

    // wave-level (64-lane) inclusive scan of per-thread counts
    const int lane = tid & 63;
    const int wid  = tid >> 6;              // 0..3
    int incl = cnt;
    #pragma unroll
    for (int d = 1; d < 64; d <<= 1) {
        int v = __shfl_up(incl, d, 64);
        if (lane >= d) incl += v;
    }

    __shared__ int wsum[4];
    if (lane == 63) wsum[wid] = incl;

    // zero-fill the output row before the barrier; scatter after
    const int4 z = make_int4(0, 0, 0, 0);
    *(int4*)(orow + t0)     = z;
    *(int4*)(orow + t0 + 4) = z;

    __syncthreads();

    int wbase = 0;
    #pragma unroll
    for (int w = 0; w < 4; ++w)
        if (w < wid) wbase += wsum[w];
    const int base2 = wbase + (incl - cnt); // exclusive prefix for this thread

    #pragma unroll
    for (int i = 0; i < PER; ++i) {
        if (kpos[i] >= 0) orow[base2 + kpos[i]] = tok[i];
    }
}

extern "C" void kernel_launch(void* const* d_in, const int* in_sizes, int n_in,
                              void* d_out, int out_size, void* d_ws, size_t ws_size,
                              hipStream_t stream) {
    const float* logits = (const float*)d_in[0];
    int* out = (int*)d_out;
    int* tokens = (int*)d_ws;               // N*T int32 = 1 MiB scratch

    void* args[] = { (void*)&logits, (void*)&tokens, (void*)&out };
    hipLaunchCooperativeKernel((const void*)fused_kernel,
                               dim3(N * 8), dim3(256), args, 0, stream);
}

// Round 4
// 27.758 us; speedup vs baseline: 4.5099x; 4.5099x over previous
//
#include <hip/hip_runtime.h>

// BeamCTCDecoder — degenerate beam search == per-step argmax, then CTC collapse.
// logits: (N=128, C=128, T=2048) float32, layout n*C*T + c*T + t.
// out: (N, T) int32 — collapsed tokens, blank(0)-padded.

constexpr int N = 128;
constexpr int C = 128;
constexpr int T = 2048;

// ---------------- Kernel A: argmax over classes, 4-way c-split ----------------
// Block = 256 threads = 4 waves; wave g scans classes [g*32, g*32+32) for the
// same 64 t-quads (256 consecutive t's -> 1 KiB contiguous per wave load).
// 8 blocks/row -> 1024 blocks -> 4 blocks/CU, 16 waves/CU.
// Inner loop: explicit 8-deep float4 batches to force 8 loads in flight.
__global__ __launch_bounds__(256) void argmax_kernel(const float* __restrict__ logits,
                                                     int* __restrict__ tokens) {
    __shared__ float sb[3][4][64];   // [group-1][component][tq] — stride-4B, conflict-free
    __shared__ int   si[3][4][64];

    const int tid = threadIdx.x;
    const int tq  = tid & 63;            // t-quad slot (== lane)
    const int grp = tid >> 6;            // c-group 0..3 (== wave id)
    const int b   = blockIdx.x;
    const int n   = b >> 3;              // 8 blocks per row
    const int t4  = (b & 7) * 256 + tq * 4;

    const float* base = logits + (size_t)n * C * T + (size_t)(grp * 32) * T + t4;

    float4 best = make_float4(-__builtin_inff(), -__builtin_inff(),
                              -__builtin_inff(), -__builtin_inff());
    int4 bidx = make_int4(0, 0, 0, 0);

    #pragma unroll
    for (int cc = 0; cc < 32; cc += 8) {
        float4 v[8];
        #pragma unroll
        for (int j = 0; j < 8; ++j)
            v[j] = *(const float4*)(base + (size_t)(cc + j) * T);
        #pragma unroll
        for (int j = 0; j < 8; ++j) {
            const int c = cc + j;
            // strict > keeps the FIRST max (matches jnp.argmax tie-break)
            if (v[j].x > best.x) { best.x = v[j].x; bidx.x = c; }
            if (v[j].y > best.y) { best.y = v[j].y; bidx.y = c; }
            if (v[j].z > best.z) { best.z = v[j].z; bidx.z = c; }
            if (v[j].w > best.w) { best.w = v[j].w; bidx.w = c; }
        }
    }

    if (grp > 0) {                                      // waves 1-3 publish (scalar, conflict-free)
        sb[grp - 1][0][tq] = best.x; si[grp - 1][0][tq] = bidx.x + grp * 32;
        sb[grp - 1][1][tq] = best.y; si[grp - 1][1][tq] = bidx.y + grp * 32;
        sb[grp - 1][2][tq] = best.z; si[grp - 1][2][tq] = bidx.z + grp * 32;
        sb[grp - 1][3][tq] = best.w; si[grp - 1][3][tq] = bidx.w + grp * 32;
    }
    __syncthreads();
    if (grp == 0) {                                     // wave 0 combines + writes
        #pragma unroll
        for (int g = 0; g < 3; ++g) {
            // higher groups win only on strict > -> ties keep lowest class
            float f;
            f = sb[g][0][tq]; if (f > best.x) { best.x = f; bidx.x = si[g][0][tq]; }
            f = sb[g][1][tq]; if (f > best.y) { best.y = f; bidx.y = si[g][1][tq]; }
            f = sb[g][2][tq]; if (f > best.z) { best.z = f; bidx.z = si[g][2][tq]; }
            f = sb[g][3][tq]; if (f > best.w) { best.w = f; bidx.w = si[g][3][tq]; }
        }
        *(int4*)(tokens + (size_t)n * T + t4) = bidx;
    }
}

// ---------------- Kernel B: per-row CTC collapse ----------------
// One block (256 threads) per row n; each thread owns 8 consecutive t's.
__global__ __launch_bounds__(256) void collapse_kernel(const int* __restrict__ tokens,
                                                       int* __restrict__ out) {
    const int n = blockIdx.x;
    const int* trow = tokens + (size_t)n * T;
    int* orow = out + (size_t)n * T;
    const int tid = threadIdx.x;            // 0..255
    constexpr int PER = T / 256;            // 8
    const int t0 = tid * PER;

    int tok[PER];
    *(int4*)&tok[0] = *(const int4*)(trow + t0);
    *(int4*)&tok[4] = *(const int4*)(trow + t0 + 4);
    int prev = (t0 == 0) ? -1 : trow[t0 - 1];

    int kpos[PER];
    int cnt = 0;
    #pragma unroll
    for (int i = 0; i < PER; ++i) {
        const bool k = (tok[i] != 0) && (tok[i] != prev);
        kpos[i] = k ? cnt : -1;
        cnt += k ? 1 : 0;
        prev = tok[i];
    }

    // wave-level (64-lane) inclusive scan of per-thread counts
    const int lane = tid & 63;
    const int wid  = tid >> 6;              // 0..3
    int incl = cnt;
    #pragma unroll
    for (int d = 1; d < 64; d <<= 1) {
        int v = __shfl_up(incl, d, 64);
        if (lane >= d) incl += v;
    }

    __shared__ int wsum[4];
    if (lane == 63) wsum[wid] = incl;

    // zero-fill the output row before the barrier; scatter after
    const int4 z = make_int4(0, 0, 0, 0);
    *(int4*)(orow + t0)     = z;
    *(int4*)(orow + t0 + 4) = z;

    __syncthreads();

    int wbase = 0;
    #pragma unroll
    for (int w = 0; w < 4; ++w)
        if (w < wid) wbase += wsum[w];
    const int base2 = wbase + (incl - cnt); // exclusive prefix for this thread

    #pragma unroll
    for (int i = 0; i < PER; ++i) {
        if (kpos[i] >= 0) orow[base2 + kpos[i]] = tok[i];
    }
}

extern "C" void kernel_launch(void* const* d_in, const int* in_sizes, int n_in,
                              void* d_out, int out_size, void* d_ws, size_t ws_size,
                              hipStream_t stream) {
    const float* logits = (const float*)d_in[0];
    int* out = (int*)d_out;
    int* tokens = (int*)d_ws;               // N*T int32 = 1 MiB scratch

    argmax_kernel<<<N * 8, 256, 0, stream>>>(logits, tokens);
    collapse_kernel<<<N, 256, 0, stream>>>(tokens, out);
}